// Round 1
// baseline (2307.203 us; speedup 1.0000x reference)
//
#include <hip/hip_runtime.h>

#define NRELS 4
#define HDIM 128
#define MAXDEG 10
#define NBUCK 11

// ---------------------------------------------------------------- precompute
__global__ void count_edges(const int* __restrict__ dst, const int* __restrict__ rel,
                            int* __restrict__ cnt, int* __restrict__ deg, int E) {
  int e = blockIdx.x * 256 + threadIdx.x;
  if (e < E) {
    int d = dst[e];
    atomicAdd(&cnt[d * 4 + rel[e]], 1);
    atomicAdd(&deg[d], 1);
  }
}

__global__ void prep_nodes(const int* __restrict__ cnt, const int* __restrict__ deg,
                           float* __restrict__ inv, int* __restrict__ bucket,
                           int* __restrict__ hist, int N) {
  int n = blockIdx.x * 256 + threadIdx.x;
  int b = -1;
  if (n < N) {
    for (int r = 0; r < 4; r++) {
      int c = cnt[n * 4 + r];
      inv[n * 4 + r] = 1.0f / (float)(c > 1 ? c : 1);
    }
    int d = deg[n];
    b = d < MAXDEG ? d : MAXDEG;
    bucket[n] = b;
  }
  int lane = threadIdx.x & 63;
  // wave-aggregated histogram (avoid 48K same-address atomics on bucket 10)
  for (int bb = 0; bb < NBUCK; bb++) {
    unsigned long long m = __ballot(b == bb);
    if (m == 0ULL) continue;
    int leader = __ffsll(m) - 1;
    if (lane == leader) atomicAdd(&hist[bb], __popcll(m));
  }
}

__global__ void calc_offsets(const int* __restrict__ hist, int* __restrict__ off,
                             int* __restrict__ fill) {
  if (threadIdx.x == 0) {
    int acc = 0;
    for (int b = 0; b < NBUCK; b++) {
      off[b] = acc;
      fill[b] = acc;
      acc += ((hist[b] + 63) >> 6) << 6;  // pad each bucket to a multiple of 64
    }
    off[NBUCK] = acc;
  }
}

__global__ void build_perm(const int* __restrict__ bucket, int* __restrict__ fill,
                           int* __restrict__ perm, int N) {
  int n = blockIdx.x * 256 + threadIdx.x;
  int b = (n < N) ? bucket[n] : -1;
  int lane = threadIdx.x & 63;
  for (int bb = 0; bb < NBUCK; bb++) {
    unsigned long long m = __ballot(b == bb);
    if (m == 0ULL) continue;
    int leader = __ffsll(m) - 1;
    int base = 0;
    if (lane == leader) base = atomicAdd(&fill[bb], __popcll(m));
    base = __shfl(base, leader);
    if (b == bb) {
      int idx = __popcll(m & ((1ULL << lane) - 1ULL));
      perm[base + idx] = n;
    }
  }
}

// ---------------------------------------------------------------- scatters
__global__ void rgcn_scatter(const float* __restrict__ h, const int* __restrict__ src,
                             const int* __restrict__ dst, const int* __restrict__ rel,
                             const float* __restrict__ inv, float* __restrict__ agg, int E) {
  int e = blockIdx.x * 2 + (threadIdx.x >> 7);
  if (e >= E) return;
  int c = threadIdx.x & 127;
  int s = src[e], d = dst[e], r = rel[e];
  float w = inv[d * 4 + r];  // fold the mean into the scatter
  atomicAdd(&agg[((size_t)d * 4 + r) * 128 + c], h[(size_t)s * 128 + c] * w);
}

__global__ void mf_scatter(const float* __restrict__ h, const int* __restrict__ src,
                           const int* __restrict__ dst, float* __restrict__ agg, int E) {
  int e = blockIdx.x * 2 + (threadIdx.x >> 7);
  if (e >= E) return;
  int c = threadIdx.x & 127;
  int s = src[e], d = dst[e];
  atomicAdd(&agg[(size_t)d * 128 + c], h[(size_t)s * 128 + c]);
}

// ---------------------------------------------------------------- GEMMs
// tile: 64 rows x 128 cols, BK=32, 256 threads; thread = 4 rows x 8 cols
__global__ __launch_bounds__(256) void embed_gemm(const float* __restrict__ x,
                                                  const float* __restrict__ W,
                                                  const float* __restrict__ bias,
                                                  float* __restrict__ out, int N) {
  __shared__ float As[64][33];
  __shared__ float Ws[32][128];
  int tid = threadIdx.x;
  int row0 = blockIdx.x * 64;
  int tx = tid & 15, ty = tid >> 4;
  int tx8 = tx * 8, ty4 = ty * 4;
  float acc[4][8];
#pragma unroll
  for (int j = 0; j < 8; j++) {
    float bv = bias[tx8 + j];
#pragma unroll
    for (int i = 0; i < 4; i++) acc[i][j] = bv;
  }
#pragma unroll
  for (int l = 0; l < 8; l++) {
    int lin = tid + l * 256;
    int r = lin >> 5, kk = lin & 31;
    int n = row0 + r;
    As[r][kk] = (n < N) ? x[(size_t)n * 32 + kk] : 0.f;
  }
#pragma unroll
  for (int l = 0; l < 16; l++) {
    int lin = tid + l * 256;
    Ws[lin >> 7][lin & 127] = W[lin];
  }
  __syncthreads();
#pragma unroll
  for (int kk = 0; kk < 32; kk++) {
    float a[4];
#pragma unroll
    for (int i = 0; i < 4; i++) a[i] = As[ty4 + i][kk];
    float4 w0 = *(const float4*)&Ws[kk][tx8];
    float4 w1 = *(const float4*)&Ws[kk][tx8 + 4];
    float w[8] = {w0.x, w0.y, w0.z, w0.w, w1.x, w1.y, w1.z, w1.w};
#pragma unroll
    for (int i = 0; i < 4; i++)
#pragma unroll
      for (int j = 0; j < 8; j++) acc[i][j] += a[i] * w[j];
  }
#pragma unroll
  for (int i = 0; i < 4; i++) {
    int n = row0 + ty4 + i;
    if (n < N) {
      float4 o0 = {acc[i][0], acc[i][1], acc[i][2], acc[i][3]};
      float4 o1 = {acc[i][4], acc[i][5], acc[i][6], acc[i][7]};
      *(float4*)&out[(size_t)n * 128 + tx8] = o0;
      *(float4*)&out[(size_t)n * 128 + tx8 + 4] = o1;
    }
  }
}

// C[n,:] = relu( concat_r(agg[n,r,:]) @ Wrel + h[n,:] @ Wroot + b )   K = 640
__global__ __launch_bounds__(256) void rgcn_gemm(const float* __restrict__ agg,
                                                 const float* __restrict__ h,
                                                 const float* __restrict__ Wrel,
                                                 const float* __restrict__ Wroot,
                                                 const float* __restrict__ bias,
                                                 float* __restrict__ out, int N) {
  __shared__ float As[64][33];
  __shared__ float Ws[32][128];
  int tid = threadIdx.x;
  int row0 = blockIdx.x * 64;
  int tx = tid & 15, ty = tid >> 4;
  int tx8 = tx * 8, ty4 = ty * 4;
  float acc[4][8];
#pragma unroll
  for (int j = 0; j < 8; j++) {
    float bv = bias[tx8 + j];
#pragma unroll
    for (int i = 0; i < 4; i++) acc[i][j] = bv;
  }
  for (int kt = 0; kt < 20; kt++) {
    int kbase = kt * 32;
#pragma unroll
    for (int l = 0; l < 8; l++) {
      int lin = tid + l * 256;
      int r = lin >> 5, kk = lin & 31;
      int n = row0 + r;
      float v = 0.f;
      if (n < N) {
        int k = kbase + kk;
        v = (k < 512) ? agg[(size_t)n * 512 + k] : h[(size_t)n * 128 + (k - 512)];
      }
      As[r][kk] = v;
    }
    const float* Wsrc =
        (kbase < 512) ? (Wrel + (size_t)kbase * 128) : (Wroot + (size_t)(kbase - 512) * 128);
#pragma unroll
    for (int l = 0; l < 16; l++) {
      int lin = tid + l * 256;
      Ws[lin >> 7][lin & 127] = Wsrc[lin];
    }
    __syncthreads();
#pragma unroll
    for (int kk = 0; kk < 32; kk++) {
      float a[4];
#pragma unroll
      for (int i = 0; i < 4; i++) a[i] = As[ty4 + i][kk];
      float4 w0 = *(const float4*)&Ws[kk][tx8];
      float4 w1 = *(const float4*)&Ws[kk][tx8 + 4];
      float w[8] = {w0.x, w0.y, w0.z, w0.w, w1.x, w1.y, w1.z, w1.w};
#pragma unroll
      for (int i = 0; i < 4; i++)
#pragma unroll
        for (int j = 0; j < 8; j++) acc[i][j] += a[i] * w[j];
    }
    __syncthreads();
  }
#pragma unroll
  for (int i = 0; i < 4; i++) {
    int n = row0 + ty4 + i;
    if (n < N) {
      float4 o0 = {fmaxf(acc[i][0], 0.f), fmaxf(acc[i][1], 0.f), fmaxf(acc[i][2], 0.f),
                   fmaxf(acc[i][3], 0.f)};
      float4 o1 = {fmaxf(acc[i][4], 0.f), fmaxf(acc[i][5], 0.f), fmaxf(acc[i][6], 0.f),
                   fmaxf(acc[i][7], 0.f)};
      *(float4*)&out[(size_t)n * 128 + tx8] = o0;
      *(float4*)&out[(size_t)n * 128 + tx8 + 4] = o1;
    }
  }
}

// degree-bucketed grouped GEMM: C[n,:] = agg[n,:]@Wl[b] + h[n,:]@Wr[b] + bl[b]   K = 256
__global__ __launch_bounds__(256) void mf_gemm(const float* __restrict__ aggmf,
                                               const float* __restrict__ h,
                                               const float* __restrict__ Wl,
                                               const float* __restrict__ Wr,
                                               const float* __restrict__ bl,
                                               const int* __restrict__ perm,
                                               const int* __restrict__ off,
                                               float* __restrict__ out, int relu_out) {
  __shared__ float As[64][33];
  __shared__ float Ws[32][128];
  __shared__ int nodes[64];
  __shared__ int soff[12];
  int tid = threadIdx.x;
  int row0 = blockIdx.x * 64;
  if (tid < 12) soff[tid] = off[tid];
  if (tid >= 64 && tid < 128) nodes[tid - 64] = perm[row0 + tid - 64];
  __syncthreads();
  if (row0 >= soff[11]) return;  // uniform per block
  int b = 0;
  while (b < 10 && row0 >= soff[b + 1]) b++;
  const float* Wlb = Wl + (size_t)b * 16384;
  const float* Wrb = Wr + (size_t)b * 16384;
  const float* blb = bl + b * 128;
  int tx = tid & 15, ty = tid >> 4;
  int tx8 = tx * 8, ty4 = ty * 4;
  float acc[4][8];
#pragma unroll
  for (int j = 0; j < 8; j++) {
    float bv = blb[tx8 + j];
#pragma unroll
    for (int i = 0; i < 4; i++) acc[i][j] = bv;
  }
  for (int kt = 0; kt < 8; kt++) {
    int kbase = kt * 32;
#pragma unroll
    for (int l = 0; l < 8; l++) {
      int lin = tid + l * 256;
      int r = lin >> 5, kk = lin & 31;
      int n = nodes[r];
      float v = 0.f;
      if (n >= 0) {
        int k = kbase + kk;
        v = (k < 128) ? aggmf[(size_t)n * 128 + k] : h[(size_t)n * 128 + (k - 128)];
      }
      As[r][kk] = v;
    }
    const float* Wsrc =
        (kbase < 128) ? (Wlb + (size_t)kbase * 128) : (Wrb + (size_t)(kbase - 128) * 128);
#pragma unroll
    for (int l = 0; l < 16; l++) {
      int lin = tid + l * 256;
      Ws[lin >> 7][lin & 127] = Wsrc[lin];
    }
    __syncthreads();
#pragma unroll
    for (int kk = 0; kk < 32; kk++) {
      float a[4];
#pragma unroll
      for (int i = 0; i < 4; i++) a[i] = As[ty4 + i][kk];
      float4 w0 = *(const float4*)&Ws[kk][tx8];
      float4 w1 = *(const float4*)&Ws[kk][tx8 + 4];
      float w[8] = {w0.x, w0.y, w0.z, w0.w, w1.x, w1.y, w1.z, w1.w};
#pragma unroll
      for (int i = 0; i < 4; i++)
#pragma unroll
        for (int j = 0; j < 8; j++) acc[i][j] += a[i] * w[j];
    }
    __syncthreads();
  }
#pragma unroll
  for (int i = 0; i < 4; i++) {
    int n = nodes[ty4 + i];
    if (n >= 0) {
      float v[8];
#pragma unroll
      for (int j = 0; j < 8; j++) v[j] = relu_out ? fmaxf(acc[i][j], 0.f) : acc[i][j];
      float4 o0 = {v[0], v[1], v[2], v[3]};
      float4 o1 = {v[4], v[5], v[6], v[7]};
      *(float4*)&out[(size_t)n * 128 + tx8] = o0;
      *(float4*)&out[(size_t)n * 128 + tx8 + 4] = o1;
    }
  }
}

// ---------------------------------------------------------------- pool + head
__global__ void pool_kernel(const float* __restrict__ h, const int* __restrict__ batch,
                            float* __restrict__ g, int N) {
  int base = blockIdx.x * 64;
  int c = threadIdx.x;  // 128 threads
  float sum = 0.f;
  int cur = -1;
  int end = (base + 64 < N) ? base + 64 : N;
  for (int n = base; n < end; n++) {
    int b = batch[n];
    if (b != cur) {
      if (cur >= 0) atomicAdd(&g[cur * 128 + c], sum);
      cur = b;
      sum = 0.f;
    }
    sum += h[(size_t)n * 128 + c];
  }
  if (cur >= 0) atomicAdd(&g[cur * 128 + c], sum);
}

__global__ void head_kernel(const float* __restrict__ g, const float* __restrict__ W1,
                            const float* __restrict__ b1, const float* __restrict__ W2,
                            const float* __restrict__ b2, float* __restrict__ out) {
  int bg = blockIdx.x;
  int o = threadIdx.x;  // 128
  __shared__ float gs[128];
  __shared__ float red[128];
  gs[o] = g[bg * 128 + o];
  __syncthreads();
  float acc = b1[o];
  for (int k = 0; k < 128; k++) acc += gs[k] * W1[k * 128 + o];
  acc = fmaxf(acc, 0.f);
  red[o] = acc * W2[o];
  __syncthreads();
  for (int s = 64; s > 0; s >>= 1) {
    if (o < s) red[o] += red[o + s];
    __syncthreads();
  }
  if (o == 0) out[bg] = red[0] + b2[0];
}

// ---------------------------------------------------------------- launch
extern "C" void kernel_launch(void* const* d_in, const int* in_sizes, int n_in,
                              void* d_out, int out_size, void* d_ws, size_t ws_size,
                              hipStream_t stream) {
  const float* x = (const float*)d_in[0];
  const int* ei = (const int*)d_in[1];
  const int* ea = (const int*)d_in[2];
  const int* batch = (const int*)d_in[3];
  const float* embW = (const float*)d_in[4];
  const float* embB = (const float*)d_in[5];
  const float* Wrel = (const float*)d_in[6];
  const float* Wroot = (const float*)d_in[7];
  const float* rb = (const float*)d_in[8];
  const float* Wl = (const float*)d_in[9];
  const float* bl = (const float*)d_in[10];
  const float* Wr = (const float*)d_in[11];
  const float* l1W = (const float*)d_in[12];
  const float* l1b = (const float*)d_in[13];
  const float* l2W = (const float*)d_in[14];
  const float* l2b = (const float*)d_in[15];
  float* out = (float*)d_out;

  int N = in_sizes[0] / 32;
  int E = in_sizes[2];
  int G = out_size;

  char* p = (char*)d_ws;
  auto alloc = [&](size_t bytes) {
    char* r = p;
    p += (bytes + 255) & ~(size_t)255;
    return r;
  };
  float* h = (float*)alloc((size_t)N * 128 * 4);
  float* h2 = (float*)alloc((size_t)N * 128 * 4);
  float* agg = (float*)alloc((size_t)N * 512 * 4);  // RGCN agg; MF agg aliases front
  float* inv = (float*)alloc((size_t)N * 4 * 4);
  int* cnt = (int*)alloc((size_t)N * 4 * 4);
  int* deg = (int*)alloc((size_t)N * 4);
  int* bucket = (int*)alloc((size_t)N * 4);
  int permCap = ((N + 63) / 64 + NBUCK) * 64;
  int* perm = (int*)alloc((size_t)permCap * 4);
  int* hist = (int*)alloc(64);
  int* off = (int*)alloc(64);
  int* fill = (int*)alloc(64);
  float* g = (float*)alloc((size_t)G * 128 * 4);

  hipMemsetAsync(cnt, 0, (size_t)N * 4 * 4, stream);
  hipMemsetAsync(deg, 0, (size_t)N * 4, stream);
  hipMemsetAsync(hist, 0, 64, stream);
  hipMemsetAsync(g, 0, (size_t)G * 128 * 4, stream);
  hipMemsetAsync(perm, 0xFF, (size_t)permCap * 4, stream);

  const int* src = ei;
  const int* dst = ei + E;

  count_edges<<<(E + 255) / 256, 256, 0, stream>>>(dst, ea, cnt, deg, E);
  prep_nodes<<<(N + 255) / 256, 256, 0, stream>>>(cnt, deg, inv, bucket, hist, N);
  calc_offsets<<<1, 64, 0, stream>>>(hist, off, fill);
  build_perm<<<(N + 255) / 256, 256, 0, stream>>>(bucket, fill, perm, N);

  int nb = (N + 63) / 64;
  embed_gemm<<<nb, 256, 0, stream>>>(x, embW, embB, h, N);

  int mfblocks = permCap / 64;
  for (int blk = 0; blk < 2; blk++) {
    hipMemsetAsync(agg, 0, (size_t)N * 512 * 4, stream);
    rgcn_scatter<<<(E + 1) / 2, 256, 0, stream>>>(h, src, dst, ea, inv, agg, E);
    rgcn_gemm<<<nb, 256, 0, stream>>>(agg, h, Wrel + (size_t)blk * 4 * 128 * 128,
                                      Wroot + (size_t)blk * 128 * 128, rb + blk * 128, h2, N);
    hipMemsetAsync(agg, 0, (size_t)N * 128 * 4, stream);
    mf_scatter<<<(E + 1) / 2, 256, 0, stream>>>(h2, src, dst, agg, E);
    mf_gemm<<<mfblocks, 256, 0, stream>>>(
        agg, h2, Wl + (size_t)blk * 11 * 128 * 128, Wr + (size_t)blk * 11 * 128 * 128,
        bl + (size_t)blk * 11 * 128, perm, off, h, (blk == 0) ? 1 : 0);
  }
  pool_kernel<<<(N + 63) / 64, 128, 0, stream>>>(h, batch, g, N);
  head_kernel<<<G, 128, 0, stream>>>(g, l1W, l1b, l2W, l2b, out);
}

// Round 2
// 1366.024 us; speedup vs baseline: 1.6890x; 1.6890x over previous
//
#include <hip/hip_runtime.h>

#define NRELS 4
#define MAXDEG 10
#define NBUCK 11
#define POOL_CHUNKS 8

// ---------------------------------------------------------------- precompute
__global__ void count_edges(const int* __restrict__ dst, const int* __restrict__ rel,
                            int* __restrict__ cnt, int E) {
  int e = blockIdx.x * 256 + threadIdx.x;
  if (e < E) atomicAdd(&cnt[dst[e] * 4 + rel[e]], 1);
}

__global__ void prep_nodes(const int* __restrict__ cnt, float* __restrict__ inv,
                           int* __restrict__ bucket, int* __restrict__ hist, int N) {
  int n = blockIdx.x * 256 + threadIdx.x;
  int b = -1;
  if (n < N) {
    int d = 0;
    for (int r = 0; r < 4; r++) {
      int c = cnt[n * 4 + r];
      d += c;
      inv[n * 4 + r] = 1.0f / (float)(c > 1 ? c : 1);
    }
    b = d < MAXDEG ? d : MAXDEG;
    bucket[n] = b;
  }
  int lane = threadIdx.x & 63;
  for (int bb = 0; bb < NBUCK; bb++) {
    unsigned long long m = __ballot(b == bb);
    if (m == 0ULL) continue;
    int leader = __ffsll(m) - 1;
    if (lane == leader) atomicAdd(&hist[bb], __popcll(m));
  }
}

__global__ void calc_offsets(const int* __restrict__ hist, int* __restrict__ off,
                             int* __restrict__ fill) {
  if (threadIdx.x == 0) {
    int acc = 0;
    for (int b = 0; b < NBUCK; b++) {
      off[b] = acc;
      fill[b] = acc;
      acc += ((hist[b] + 63) >> 6) << 6;
    }
    off[NBUCK] = acc;
  }
}

__global__ void build_perm(const int* __restrict__ bucket, int* __restrict__ fill,
                           int* __restrict__ perm, int N) {
  int n = blockIdx.x * 256 + threadIdx.x;
  int b = (n < N) ? bucket[n] : -1;
  int lane = threadIdx.x & 63;
  for (int bb = 0; bb < NBUCK; bb++) {
    unsigned long long m = __ballot(b == bb);
    if (m == 0ULL) continue;
    int leader = __ffsll(m) - 1;
    int base = 0;
    if (lane == leader) base = atomicAdd(&fill[bb], __popcll(m));
    base = __shfl(base, leader);
    if (b == bb) {
      int idx = __popcll(m & ((1ULL << lane) - 1ULL));
      perm[base + idx] = n;
    }
  }
}

// segment slot allocation: arbitrary segment order is fine (sum is order-free)
__global__ void assign_segments(const int* __restrict__ cnt, int* __restrict__ seg_start,
                                int* __restrict__ seg_cur, int* __restrict__ cursor, int NSEG) {
  __shared__ int sd[256];
  __shared__ int sbase;
  int t = threadIdx.x;
  int s = blockIdx.x * 256 + t;
  int v = (s < NSEG) ? cnt[s] : 0;
  sd[t] = v;
  __syncthreads();
  for (int o = 1; o < 256; o <<= 1) {
    int x = (t >= o) ? sd[t - o] : 0;
    __syncthreads();
    sd[t] += x;
    __syncthreads();
  }
  if (t == 255) sbase = atomicAdd(cursor, sd[255]);
  __syncthreads();
  if (s < NSEG) {
    int st = sbase + sd[t] - v;
    seg_start[s] = st;
    seg_cur[s] = st;
  }
}

__global__ void place_edges(const int* __restrict__ src, const int* __restrict__ dst,
                            const int* __restrict__ rel, int* __restrict__ seg_cur,
                            int* __restrict__ csr, int E) {
  int e = blockIdx.x * 256 + threadIdx.x;
  if (e >= E) return;
  int seg = dst[e] * 4 + rel[e];
  int pos = atomicAdd(&seg_cur[seg], 1);
  csr[pos] = src[e];
}

// ---------------------------------------------------------------- gathers (no atomics)
__global__ void rgcn_gather(const float* __restrict__ h, const int* __restrict__ csr,
                            const int* __restrict__ seg_start, const int* __restrict__ cnt,
                            const float* __restrict__ inv, float* __restrict__ agg, int N) {
  int n = blockIdx.x * 2 + (threadIdx.x >> 7);
  if (n >= N) return;
  int c = threadIdx.x & 127;
  for (int r = 0; r < 4; r++) {
    int seg = n * 4 + r;
    int st = seg_start[seg];
    int cn = cnt[seg];
    float s = 0.f;
    int i = 0;
    for (; i + 2 <= cn; i += 2) {
      int s0 = csr[st + i], s1 = csr[st + i + 1];
      float v0 = h[(size_t)s0 * 128 + c];
      float v1 = h[(size_t)s1 * 128 + c];
      s += v0 + v1;
    }
    if (i < cn) s += h[(size_t)csr[st + i] * 128 + c];
    agg[(size_t)n * 512 + r * 128 + c] = s * inv[seg];
  }
}

__global__ void mf_gather(const float* __restrict__ h, const int* __restrict__ csr,
                          const int* __restrict__ seg_start, const int* __restrict__ cnt,
                          float* __restrict__ aggmf, int N) {
  int n = blockIdx.x * 2 + (threadIdx.x >> 7);
  if (n >= N) return;
  int c = threadIdx.x & 127;
  float s = 0.f;
  for (int r = 0; r < 4; r++) {
    int seg = n * 4 + r;
    int st = seg_start[seg], cn = cnt[seg];
    int i = 0;
    for (; i + 2 <= cn; i += 2) {
      int s0 = csr[st + i], s1 = csr[st + i + 1];
      s += h[(size_t)s0 * 128 + c] + h[(size_t)s1 * 128 + c];
    }
    if (i < cn) s += h[(size_t)csr[st + i] * 128 + c];
  }
  aggmf[(size_t)n * 128 + c] = s;
}

// ---------------------------------------------------------------- GEMMs
__global__ __launch_bounds__(256) void embed_gemm(const float* __restrict__ x,
                                                  const float* __restrict__ W,
                                                  const float* __restrict__ bias,
                                                  float* __restrict__ out, int N) {
  __shared__ float As[64][33];
  __shared__ float Ws[32][128];
  int tid = threadIdx.x;
  int row0 = blockIdx.x * 64;
  int tx = tid & 15, ty = tid >> 4;
  int tx8 = tx * 8, ty4 = ty * 4;
  float acc[4][8];
#pragma unroll
  for (int j = 0; j < 8; j++) {
    float bv = bias[tx8 + j];
#pragma unroll
    for (int i = 0; i < 4; i++) acc[i][j] = bv;
  }
#pragma unroll
  for (int l = 0; l < 8; l++) {
    int lin = tid + l * 256;
    int r = lin >> 5, kk = lin & 31;
    int n = row0 + r;
    As[r][kk] = (n < N) ? x[(size_t)n * 32 + kk] : 0.f;
  }
#pragma unroll
  for (int l = 0; l < 16; l++) {
    int lin = tid + l * 256;
    Ws[lin >> 7][lin & 127] = W[lin];
  }
  __syncthreads();
#pragma unroll
  for (int kk = 0; kk < 32; kk++) {
    float a[4];
#pragma unroll
    for (int i = 0; i < 4; i++) a[i] = As[ty4 + i][kk];
    float4 w0 = *(const float4*)&Ws[kk][tx8];
    float4 w1 = *(const float4*)&Ws[kk][tx8 + 4];
    float w[8] = {w0.x, w0.y, w0.z, w0.w, w1.x, w1.y, w1.z, w1.w};
#pragma unroll
    for (int i = 0; i < 4; i++)
#pragma unroll
      for (int j = 0; j < 8; j++) acc[i][j] += a[i] * w[j];
  }
#pragma unroll
  for (int i = 0; i < 4; i++) {
    int n = row0 + ty4 + i;
    if (n < N) {
      float4 o0 = {acc[i][0], acc[i][1], acc[i][2], acc[i][3]};
      float4 o1 = {acc[i][4], acc[i][5], acc[i][6], acc[i][7]};
      *(float4*)&out[(size_t)n * 128 + tx8] = o0;
      *(float4*)&out[(size_t)n * 128 + tx8 + 4] = o1;
    }
  }
}

__global__ __launch_bounds__(256) void rgcn_gemm(const float* __restrict__ agg,
                                                 const float* __restrict__ h,
                                                 const float* __restrict__ Wrel,
                                                 const float* __restrict__ Wroot,
                                                 const float* __restrict__ bias,
                                                 float* __restrict__ out, int N) {
  __shared__ float As[64][33];
  __shared__ float Ws[32][128];
  int tid = threadIdx.x;
  int row0 = blockIdx.x * 64;
  int tx = tid & 15, ty = tid >> 4;
  int tx8 = tx * 8, ty4 = ty * 4;
  float acc[4][8];
#pragma unroll
  for (int j = 0; j < 8; j++) {
    float bv = bias[tx8 + j];
#pragma unroll
    for (int i = 0; i < 4; i++) acc[i][j] = bv;
  }
  for (int kt = 0; kt < 20; kt++) {
    int kbase = kt * 32;
#pragma unroll
    for (int l = 0; l < 8; l++) {
      int lin = tid + l * 256;
      int r = lin >> 5, kk = lin & 31;
      int n = row0 + r;
      float v = 0.f;
      if (n < N) {
        int k = kbase + kk;
        v = (k < 512) ? agg[(size_t)n * 512 + k] : h[(size_t)n * 128 + (k - 512)];
      }
      As[r][kk] = v;
    }
    const float* Wsrc =
        (kbase < 512) ? (Wrel + (size_t)kbase * 128) : (Wroot + (size_t)(kbase - 512) * 128);
#pragma unroll
    for (int l = 0; l < 16; l++) {
      int lin = tid + l * 256;
      Ws[lin >> 7][lin & 127] = Wsrc[lin];
    }
    __syncthreads();
#pragma unroll
    for (int kk = 0; kk < 32; kk++) {
      float a[4];
#pragma unroll
      for (int i = 0; i < 4; i++) a[i] = As[ty4 + i][kk];
      float4 w0 = *(const float4*)&Ws[kk][tx8];
      float4 w1 = *(const float4*)&Ws[kk][tx8 + 4];
      float w[8] = {w0.x, w0.y, w0.z, w0.w, w1.x, w1.y, w1.z, w1.w};
#pragma unroll
      for (int i = 0; i < 4; i++)
#pragma unroll
        for (int j = 0; j < 8; j++) acc[i][j] += a[i] * w[j];
    }
    __syncthreads();
  }
#pragma unroll
  for (int i = 0; i < 4; i++) {
    int n = row0 + ty4 + i;
    if (n < N) {
      float4 o0 = {fmaxf(acc[i][0], 0.f), fmaxf(acc[i][1], 0.f), fmaxf(acc[i][2], 0.f),
                   fmaxf(acc[i][3], 0.f)};
      float4 o1 = {fmaxf(acc[i][4], 0.f), fmaxf(acc[i][5], 0.f), fmaxf(acc[i][6], 0.f),
                   fmaxf(acc[i][7], 0.f)};
      *(float4*)&out[(size_t)n * 128 + tx8] = o0;
      *(float4*)&out[(size_t)n * 128 + tx8 + 4] = o1;
    }
  }
}

__global__ __launch_bounds__(256) void mf_gemm(const float* __restrict__ aggmf,
                                               const float* __restrict__ h,
                                               const float* __restrict__ Wl,
                                               const float* __restrict__ Wr,
                                               const float* __restrict__ bl,
                                               const int* __restrict__ perm,
                                               const int* __restrict__ off,
                                               float* __restrict__ out, int relu_out) {
  __shared__ float As[64][33];
  __shared__ float Ws[32][128];
  __shared__ int nodes[64];
  __shared__ int soff[12];
  int tid = threadIdx.x;
  int row0 = blockIdx.x * 64;
  if (tid < 12) soff[tid] = off[tid];
  if (tid >= 64 && tid < 128) nodes[tid - 64] = perm[row0 + tid - 64];
  __syncthreads();
  if (row0 >= soff[11]) return;
  int b = 0;
  while (b < 10 && row0 >= soff[b + 1]) b++;
  const float* Wlb = Wl + (size_t)b * 16384;
  const float* Wrb = Wr + (size_t)b * 16384;
  const float* blb = bl + b * 128;
  int tx = tid & 15, ty = tid >> 4;
  int tx8 = tx * 8, ty4 = ty * 4;
  float acc[4][8];
#pragma unroll
  for (int j = 0; j < 8; j++) {
    float bv = blb[tx8 + j];
#pragma unroll
    for (int i = 0; i < 4; i++) acc[i][j] = bv;
  }
  for (int kt = 0; kt < 8; kt++) {
    int kbase = kt * 32;
#pragma unroll
    for (int l = 0; l < 8; l++) {
      int lin = tid + l * 256;
      int r = lin >> 5, kk = lin & 31;
      int n = nodes[r];
      float v = 0.f;
      if (n >= 0) {
        int k = kbase + kk;
        v = (k < 128) ? aggmf[(size_t)n * 128 + k] : h[(size_t)n * 128 + (k - 128)];
      }
      As[r][kk] = v;
    }
    const float* Wsrc =
        (kbase < 128) ? (Wlb + (size_t)kbase * 128) : (Wrb + (size_t)(kbase - 128) * 128);
#pragma unroll
    for (int l = 0; l < 16; l++) {
      int lin = tid + l * 256;
      Ws[lin >> 7][lin & 127] = Wsrc[lin];
    }
    __syncthreads();
#pragma unroll
    for (int kk = 0; kk < 32; kk++) {
      float a[4];
#pragma unroll
      for (int i = 0; i < 4; i++) a[i] = As[ty4 + i][kk];
      float4 w0 = *(const float4*)&Ws[kk][tx8];
      float4 w1 = *(const float4*)&Ws[kk][tx8 + 4];
      float w[8] = {w0.x, w0.y, w0.z, w0.w, w1.x, w1.y, w1.z, w1.w};
#pragma unroll
      for (int i = 0; i < 4; i++)
#pragma unroll
        for (int j = 0; j < 8; j++) acc[i][j] += a[i] * w[j];
    }
    __syncthreads();
  }
#pragma unroll
  for (int i = 0; i < 4; i++) {
    int n = nodes[ty4 + i];
    if (n >= 0) {
      float v[8];
#pragma unroll
      for (int j = 0; j < 8; j++) v[j] = relu_out ? fmaxf(acc[i][j], 0.f) : acc[i][j];
      float4 o0 = {v[0], v[1], v[2], v[3]};
      float4 o1 = {v[4], v[5], v[6], v[7]};
      *(float4*)&out[(size_t)n * 128 + tx8] = o0;
      *(float4*)&out[(size_t)n * 128 + tx8 + 4] = o1;
    }
  }
}

// ---------------------------------------------------------------- pool + head
__global__ void find_starts(const int* __restrict__ batch, int* __restrict__ starts,
                            int N, int G) {
  int g = threadIdx.x;
  if (g > G) return;
  int lo = 0, hi = N;
  while (lo < hi) {
    int m = (lo + hi) >> 1;
    if (batch[m] < g) lo = m + 1; else hi = m;
  }
  starts[g] = lo;
}

__global__ void pool2(const float* __restrict__ h, const int* __restrict__ starts,
                      float* __restrict__ g, int G) {
  int gr = blockIdx.x / POOL_CHUNKS;
  int ck = blockIdx.x % POOL_CHUNKS;
  int c = threadIdx.x;
  int s = starts[gr], e = starts[gr + 1];
  int len = e - s;
  int a = s + (int)(((long long)len * ck) / POOL_CHUNKS);
  int b = s + (int)(((long long)len * (ck + 1)) / POOL_CHUNKS);
  float sum = 0.f;
  int n = a;
  for (; n + 2 <= b; n += 2) sum += h[(size_t)n * 128 + c] + h[(size_t)(n + 1) * 128 + c];
  if (n < b) sum += h[(size_t)n * 128 + c];
  if (b > a) atomicAdd(&g[gr * 128 + c], sum);
}

__global__ void head_kernel(const float* __restrict__ g, const float* __restrict__ W1,
                            const float* __restrict__ b1, const float* __restrict__ W2,
                            const float* __restrict__ b2, float* __restrict__ out) {
  int bg = blockIdx.x;
  int o = threadIdx.x;
  __shared__ float gs[128];
  __shared__ float red[128];
  gs[o] = g[bg * 128 + o];
  __syncthreads();
  float acc = b1[o];
  for (int k = 0; k < 128; k++) acc += gs[k] * W1[k * 128 + o];
  acc = fmaxf(acc, 0.f);
  red[o] = acc * W2[o];
  __syncthreads();
  for (int s = 64; s > 0; s >>= 1) {
    if (o < s) red[o] += red[o + s];
    __syncthreads();
  }
  if (o == 0) out[bg] = red[0] + b2[0];
}

// ---------------------------------------------------------------- launch
extern "C" void kernel_launch(void* const* d_in, const int* in_sizes, int n_in,
                              void* d_out, int out_size, void* d_ws, size_t ws_size,
                              hipStream_t stream) {
  const float* x = (const float*)d_in[0];
  const int* ei = (const int*)d_in[1];
  const int* ea = (const int*)d_in[2];
  const int* batch = (const int*)d_in[3];
  const float* embW = (const float*)d_in[4];
  const float* embB = (const float*)d_in[5];
  const float* Wrel = (const float*)d_in[6];
  const float* Wroot = (const float*)d_in[7];
  const float* rb = (const float*)d_in[8];
  const float* Wl = (const float*)d_in[9];
  const float* bl = (const float*)d_in[10];
  const float* Wr = (const float*)d_in[11];
  const float* l1W = (const float*)d_in[12];
  const float* l1b = (const float*)d_in[13];
  const float* l2W = (const float*)d_in[14];
  const float* l2b = (const float*)d_in[15];
  float* out = (float*)d_out;

  int N = in_sizes[0] / 32;
  int E = in_sizes[2];
  int G = out_size;
  int NSEG = N * 4;

  char* p = (char*)d_ws;
  auto alloc = [&](size_t bytes) {
    char* r = p;
    p += (bytes + 255) & ~(size_t)255;
    return r;
  };
  float* h = (float*)alloc((size_t)N * 128 * 4);
  float* h2 = (float*)alloc((size_t)N * 128 * 4);
  float* agg = (float*)alloc((size_t)N * 512 * 4);  // RGCN agg; MF agg aliases the front
  float* inv = (float*)alloc((size_t)NSEG * 4);
  int* cnt = (int*)alloc((size_t)NSEG * 4);
  int* seg_start = (int*)alloc((size_t)NSEG * 4);
  int* seg_cur = (int*)alloc((size_t)NSEG * 4);
  int* csr = (int*)alloc((size_t)E * 4);
  int* bucket = (int*)alloc((size_t)N * 4);
  int permCap = ((N + 63) / 64 + NBUCK) * 64;
  int* perm = (int*)alloc((size_t)permCap * 4);
  int* hist = (int*)alloc(64);
  int* off = (int*)alloc(64);
  int* fill = (int*)alloc(64);
  int* cursor = (int*)alloc(64);
  int* starts = (int*)alloc((size_t)(G + 1) * 4);
  float* g = (float*)alloc((size_t)G * 128 * 4);

  hipMemsetAsync(cnt, 0, (size_t)NSEG * 4, stream);
  hipMemsetAsync(hist, 0, 64, stream);
  hipMemsetAsync(cursor, 0, 64, stream);
  hipMemsetAsync(g, 0, (size_t)G * 128 * 4, stream);
  hipMemsetAsync(perm, 0xFF, (size_t)permCap * 4, stream);

  const int* src = ei;
  const int* dst = ei + E;

  count_edges<<<(E + 255) / 256, 256, 0, stream>>>(dst, ea, cnt, E);
  prep_nodes<<<(N + 255) / 256, 256, 0, stream>>>(cnt, inv, bucket, hist, N);
  calc_offsets<<<1, 64, 0, stream>>>(hist, off, fill);
  build_perm<<<(N + 255) / 256, 256, 0, stream>>>(bucket, fill, perm, N);
  assign_segments<<<(NSEG + 255) / 256, 256, 0, stream>>>(cnt, seg_start, seg_cur, cursor, NSEG);
  place_edges<<<(E + 255) / 256, 256, 0, stream>>>(src, dst, ea, seg_cur, csr, E);
  find_starts<<<1, 128, 0, stream>>>(batch, starts, N, G);

  int nb = (N + 63) / 64;
  embed_gemm<<<nb, 256, 0, stream>>>(x, embW, embB, h, N);

  int mfblocks = permCap / 64;
  for (int blk = 0; blk < 2; blk++) {
    rgcn_gather<<<(N + 1) / 2, 256, 0, stream>>>(h, csr, seg_start, cnt, inv, agg, N);
    rgcn_gemm<<<nb, 256, 0, stream>>>(agg, h, Wrel + (size_t)blk * 4 * 128 * 128,
                                      Wroot + (size_t)blk * 128 * 128, rb + blk * 128, h2, N);
    mf_gather<<<(N + 1) / 2, 256, 0, stream>>>(h2, csr, seg_start, cnt, agg, N);
    mf_gemm<<<mfblocks, 256, 0, stream>>>(
        agg, h2, Wl + (size_t)blk * 11 * 128 * 128, Wr + (size_t)blk * 11 * 128 * 128,
        bl + (size_t)blk * 11 * 128, perm, off, h, (blk == 0) ? 1 : 0);
  }
  pool2<<<G * POOL_CHUNKS, 128, 0, stream>>>(h, starts, g, G);
  head_kernel<<<G, 128, 0, stream>>>(g, l1W, l1b, l2W, l2b, out);
}

// Round 3
// 813.630 us; speedup vs baseline: 2.8357x; 1.6789x over previous
//
#include <hip/hip_runtime.h>
#include <hip/hip_bf16.h>

#define NRELS 4
#define MAXDEG 10
#define NBUCK 11
#define POOL_CHUNKS 8

typedef __attribute__((ext_vector_type(8))) short s16x8;
typedef __attribute__((ext_vector_type(4))) float f32x4;
typedef __attribute__((ext_vector_type(8))) unsigned short u16x8;

__device__ inline unsigned short f2b(float f) {
  __hip_bfloat16 h = __float2bfloat16(f);
  return *reinterpret_cast<unsigned short*>(&h);
}
__device__ inline float b2f(unsigned short u) {
  union { unsigned int i; float f; } v;
  v.i = ((unsigned int)u) << 16;
  return v.f;
}

// ---------------------------------------------------------------- precompute
__global__ void count_edges(const int* __restrict__ dst, const int* __restrict__ rel,
                            int* __restrict__ cnt, int E) {
  int e = blockIdx.x * 256 + threadIdx.x;
  if (e < E) atomicAdd(&cnt[dst[e] * 4 + rel[e]], 1);
}

__global__ void prep_nodes(const int* __restrict__ cnt, float* __restrict__ inv,
                           int* __restrict__ bucket, int* __restrict__ hist, int N) {
  int n = blockIdx.x * 256 + threadIdx.x;
  int b = -1;
  if (n < N) {
    int d = 0;
    for (int r = 0; r < 4; r++) {
      int c = cnt[n * 4 + r];
      d += c;
      inv[n * 4 + r] = 1.0f / (float)(c > 1 ? c : 1);
    }
    b = d < MAXDEG ? d : MAXDEG;
    bucket[n] = b;
  }
  int lane = threadIdx.x & 63;
  for (int bb = 0; bb < NBUCK; bb++) {
    unsigned long long m = __ballot(b == bb);
    if (m == 0ULL) continue;
    int leader = __ffsll(m) - 1;
    if (lane == leader) atomicAdd(&hist[bb], __popcll(m));
  }
}

__global__ void calc_offsets(const int* __restrict__ hist, int* __restrict__ off,
                             int* __restrict__ fill) {
  if (threadIdx.x == 0) {
    int acc = 0;
    for (int b = 0; b < NBUCK; b++) {
      off[b] = acc;
      fill[b] = acc;
      acc += ((hist[b] + 63) >> 6) << 6;
    }
    off[NBUCK] = acc;
  }
}

__global__ void build_perm(const int* __restrict__ bucket, int* __restrict__ fill,
                           int* __restrict__ perm, int N) {
  int n = blockIdx.x * 256 + threadIdx.x;
  int b = (n < N) ? bucket[n] : -1;
  int lane = threadIdx.x & 63;
  for (int bb = 0; bb < NBUCK; bb++) {
    unsigned long long m = __ballot(b == bb);
    if (m == 0ULL) continue;
    int leader = __ffsll(m) - 1;
    int base = 0;
    if (lane == leader) base = atomicAdd(&fill[bb], __popcll(m));
    base = __shfl(base, leader);
    if (b == bb) {
      int idx = __popcll(m & ((1ULL << lane) - 1ULL));
      perm[base + idx] = n;
    }
  }
}

__global__ void assign_segments(const int* __restrict__ cnt, int* __restrict__ seg_start,
                                int* __restrict__ seg_cur, int* __restrict__ cursor, int NSEG) {
  __shared__ int sd[256];
  __shared__ int sbase;
  int t = threadIdx.x;
  int s = blockIdx.x * 256 + t;
  int v = (s < NSEG) ? cnt[s] : 0;
  sd[t] = v;
  __syncthreads();
  for (int o = 1; o < 256; o <<= 1) {
    int x = (t >= o) ? sd[t - o] : 0;
    __syncthreads();
    sd[t] += x;
    __syncthreads();
  }
  if (t == 255) sbase = atomicAdd(cursor, sd[255]);
  __syncthreads();
  if (s < NSEG) {
    int st = sbase + sd[t] - v;
    seg_start[s] = st;
    seg_cur[s] = st;
  }
}

__global__ void place_edges(const int* __restrict__ src, const int* __restrict__ dst,
                            const int* __restrict__ rel, int* __restrict__ seg_cur,
                            int* __restrict__ csr, int E) {
  int e = blockIdx.x * 256 + threadIdx.x;
  if (e >= E) return;
  int seg = dst[e] * 4 + rel[e];
  int pos = atomicAdd(&seg_cur[seg], 1);
  csr[pos] = src[e];
}

// ---------------------------------------------------------------- weight conversion
// Bt layout: [blk][n=128][k=640] bf16,  k<512 -> Wrel[blk][k/128][k%128][n], else Wroot
__global__ void conv_rgcn_w(const float* __restrict__ Wrel, const float* __restrict__ Wroot,
                            unsigned short* __restrict__ Bt) {
  int t = blockIdx.x * 256 + threadIdx.x;
  if (t >= 2 * 128 * 640) return;
  int blk = t / 81920;
  int rem = t % 81920;
  int n = rem / 640;
  int k = rem % 640;
  float v;
  if (k < 512)
    v = Wrel[(size_t)blk * 65536 + (size_t)k * 128 + n];
  else
    v = Wroot[(size_t)blk * 16384 + (size_t)(k - 512) * 128 + n];
  Bt[t] = f2b(v);
}

// Btm layout: [blk][b][n=128][k=256] bf16, k<128 -> Wl[blk][b][k][n], else Wr
__global__ void conv_mf_w(const float* __restrict__ Wl, const float* __restrict__ Wr,
                          unsigned short* __restrict__ Btm) {
  int t = blockIdx.x * 256 + threadIdx.x;
  if (t >= 2 * 11 * 128 * 256) return;
  int k = t & 255;
  int n = (t >> 8) & 127;
  int bb = (t >> 15) % 11;
  int blk = t / (11 * 128 * 256);
  float v;
  if (k < 128)
    v = Wl[(((size_t)blk * 11 + bb) * 128 + k) * 128 + n];
  else
    v = Wr[(((size_t)blk * 11 + bb) * 128 + (k - 128)) * 128 + n];
  Btm[t] = f2b(v);
}

// ---------------------------------------------------------------- gathers (bf16, no atomics)
// ahat[n][640]: [0..511] = per-(rel) mean agg, [512..639] = root h
__global__ void rgcn_gather(const unsigned short* __restrict__ hb, const int* __restrict__ csr,
                            const int* __restrict__ seg_start, const int* __restrict__ cnt,
                            const float* __restrict__ inv, unsigned short* __restrict__ ahat,
                            int N) {
  int n = blockIdx.x * 4 + (threadIdx.x >> 6);
  if (n >= N) return;
  int c2 = (threadIdx.x & 63) * 2;
#pragma unroll
  for (int r = 0; r < 4; r++) {
    int seg = n * 4 + r;
    int st = seg_start[seg], cn = cnt[seg];
    float s0 = 0.f, s1 = 0.f;
    int i = 0;
    for (; i + 2 <= cn; i += 2) {
      int p0 = csr[st + i], p1 = csr[st + i + 1];
      unsigned int v0 = *(const unsigned int*)(hb + (size_t)p0 * 128 + c2);
      unsigned int v1 = *(const unsigned int*)(hb + (size_t)p1 * 128 + c2);
      s0 += b2f(v0 & 0xffff) + b2f(v1 & 0xffff);
      s1 += b2f(v0 >> 16) + b2f(v1 >> 16);
    }
    if (i < cn) {
      unsigned int v0 = *(const unsigned int*)(hb + (size_t)csr[st + i] * 128 + c2);
      s0 += b2f(v0 & 0xffff);
      s1 += b2f(v0 >> 16);
    }
    float w = inv[seg];
    unsigned int o = (unsigned int)f2b(s0 * w) | ((unsigned int)f2b(s1 * w) << 16);
    *(unsigned int*)(ahat + (size_t)n * 640 + r * 128 + c2) = o;
  }
  *(unsigned int*)(ahat + (size_t)n * 640 + 512 + c2) =
      *(const unsigned int*)(hb + (size_t)n * 128 + c2);
}

// amf[n][256]: [0..127] = sum agg, [128..255] = root
__global__ void mf_gather(const unsigned short* __restrict__ hb, const int* __restrict__ csr,
                          const int* __restrict__ seg_start, const int* __restrict__ cnt,
                          unsigned short* __restrict__ amf, int N) {
  int n = blockIdx.x * 4 + (threadIdx.x >> 6);
  if (n >= N) return;
  int c2 = (threadIdx.x & 63) * 2;
  float s0 = 0.f, s1 = 0.f;
#pragma unroll
  for (int r = 0; r < 4; r++) {
    int seg = n * 4 + r;
    int st = seg_start[seg], cn = cnt[seg];
    int i = 0;
    for (; i + 2 <= cn; i += 2) {
      int p0 = csr[st + i], p1 = csr[st + i + 1];
      unsigned int v0 = *(const unsigned int*)(hb + (size_t)p0 * 128 + c2);
      unsigned int v1 = *(const unsigned int*)(hb + (size_t)p1 * 128 + c2);
      s0 += b2f(v0 & 0xffff) + b2f(v1 & 0xffff);
      s1 += b2f(v0 >> 16) + b2f(v1 >> 16);
    }
    if (i < cn) {
      unsigned int v0 = *(const unsigned int*)(hb + (size_t)csr[st + i] * 128 + c2);
      s0 += b2f(v0 & 0xffff);
      s1 += b2f(v0 >> 16);
    }
  }
  unsigned int o = (unsigned int)f2b(s0) | ((unsigned int)f2b(s1) << 16);
  *(unsigned int*)(amf + (size_t)n * 256 + c2) = o;
  *(unsigned int*)(amf + (size_t)n * 256 + 128 + c2) =
      *(const unsigned int*)(hb + (size_t)n * 128 + c2);
}

// ---------------------------------------------------------------- MFMA GEMMs
// wave computes a 16x128 strip: C = A[16 x K] @ Bt^T + bias, relu, bf16 out
__global__ __launch_bounds__(256) void rgcn_mfma(const unsigned short* __restrict__ A,
                                                 const unsigned short* __restrict__ Bt,
                                                 const float* __restrict__ bias,
                                                 unsigned short* __restrict__ out, int N) {
  int lane = threadIdx.x & 63, wave = threadIdx.x >> 6;
  int m0 = blockIdx.x * 64 + wave * 16;
  int row = lane & 15, quad = lane >> 4;
  int arow = m0 + row;
  if (arow >= N) arow = N - 1;
  const unsigned short* Ap = A + (size_t)arow * 640 + quad * 8;
  const unsigned short* Bp = Bt + (size_t)row * 640 + quad * 8;
  f32x4 acc[8];
#pragma unroll
  for (int i = 0; i < 8; i++) acc[i] = (f32x4){0.f, 0.f, 0.f, 0.f};
#pragma unroll 2
  for (int kt = 0; kt < 20; kt++) {
    s16x8 af = *(const s16x8*)(Ap + kt * 32);
#pragma unroll
    for (int nt = 0; nt < 8; nt++) {
      s16x8 bf = *(const s16x8*)(Bp + (size_t)nt * 16 * 640 + kt * 32);
      acc[nt] = __builtin_amdgcn_mfma_f32_16x16x32_bf16(af, bf, acc[nt], 0, 0, 0);
    }
  }
#pragma unroll
  for (int nt = 0; nt < 8; nt++) {
    int n = nt * 16 + row;
    float bv = bias[n];
#pragma unroll
    for (int r = 0; r < 4; r++) {
      int m = m0 + quad * 4 + r;
      if (m < N) {
        float v = fmaxf(acc[nt][r] + bv, 0.f);
        out[(size_t)m * 128 + n] = f2b(v);
      }
    }
  }
}

__global__ __launch_bounds__(256) void mf_mfma(const unsigned short* __restrict__ A,
                                               const unsigned short* __restrict__ Bt,
                                               const float* __restrict__ bl,
                                               const int* __restrict__ perm,
                                               const int* __restrict__ off,
                                               unsigned short* __restrict__ out, int relu_out) {
  __shared__ int soff[12];
  if (threadIdx.x < 12) soff[threadIdx.x] = off[threadIdx.x];
  __syncthreads();
  int row0 = blockIdx.x * 64;
  if (row0 >= soff[11]) return;
  int b = 0;
  while (b < 10 && row0 >= soff[b + 1]) b++;
  const unsigned short* Bb = Bt + (size_t)b * 128 * 256;
  const float* bb = bl + b * 128;
  int lane = threadIdx.x & 63, wave = threadIdx.x >> 6;
  int m0 = row0 + wave * 16;
  int row = lane & 15, quad = lane >> 4;
  int anode = perm[m0 + row];
  int aclamp = anode < 0 ? 0 : anode;
  const unsigned short* Ap = A + (size_t)aclamp * 256 + quad * 8;
  const unsigned short* Bp = Bb + (size_t)row * 256 + quad * 8;
  f32x4 acc[8];
#pragma unroll
  for (int i = 0; i < 8; i++) acc[i] = (f32x4){0.f, 0.f, 0.f, 0.f};
#pragma unroll
  for (int kt = 0; kt < 8; kt++) {
    s16x8 af = *(const s16x8*)(Ap + kt * 32);
#pragma unroll
    for (int nt = 0; nt < 8; nt++) {
      s16x8 bf = *(const s16x8*)(Bp + (size_t)nt * 16 * 256 + kt * 32);
      acc[nt] = __builtin_amdgcn_mfma_f32_16x16x32_bf16(af, bf, acc[nt], 0, 0, 0);
    }
  }
  int nd[4];
#pragma unroll
  for (int r = 0; r < 4; r++) nd[r] = perm[m0 + quad * 4 + r];
#pragma unroll
  for (int nt = 0; nt < 8; nt++) {
    int n = nt * 16 + row;
    float bv = bb[n];
#pragma unroll
    for (int r = 0; r < 4; r++) {
      if (nd[r] >= 0) {
        float v = acc[nt][r] + bv;
        if (relu_out) v = fmaxf(v, 0.f);
        out[(size_t)nd[r] * 128 + n] = f2b(v);
      }
    }
  }
}

// ---------------------------------------------------------------- embed (fp32 compute, bf16 out)
__global__ __launch_bounds__(256) void embed_gemm(const float* __restrict__ x,
                                                  const float* __restrict__ W,
                                                  const float* __restrict__ bias,
                                                  unsigned short* __restrict__ out, int N) {
  __shared__ float As[64][33];
  __shared__ float Ws[32][128];
  int tid = threadIdx.x;
  int row0 = blockIdx.x * 64;
  int tx = tid & 15, ty = tid >> 4;
  int tx8 = tx * 8, ty4 = ty * 4;
  float acc[4][8];
#pragma unroll
  for (int j = 0; j < 8; j++) {
    float bv = bias[tx8 + j];
#pragma unroll
    for (int i = 0; i < 4; i++) acc[i][j] = bv;
  }
#pragma unroll
  for (int l = 0; l < 8; l++) {
    int lin = tid + l * 256;
    int r = lin >> 5, kk = lin & 31;
    int n = row0 + r;
    As[r][kk] = (n < N) ? x[(size_t)n * 32 + kk] : 0.f;
  }
#pragma unroll
  for (int l = 0; l < 16; l++) {
    int lin = tid + l * 256;
    Ws[lin >> 7][lin & 127] = W[lin];
  }
  __syncthreads();
#pragma unroll
  for (int kk = 0; kk < 32; kk++) {
    float a[4];
#pragma unroll
    for (int i = 0; i < 4; i++) a[i] = As[ty4 + i][kk];
    float4 w0 = *(const float4*)&Ws[kk][tx8];
    float4 w1 = *(const float4*)&Ws[kk][tx8 + 4];
    float w[8] = {w0.x, w0.y, w0.z, w0.w, w1.x, w1.y, w1.z, w1.w};
#pragma unroll
    for (int i = 0; i < 4; i++)
#pragma unroll
      for (int j = 0; j < 8; j++) acc[i][j] += a[i] * w[j];
  }
#pragma unroll
  for (int i = 0; i < 4; i++) {
    int n = row0 + ty4 + i;
    if (n < N) {
      u16x8 o;
#pragma unroll
      for (int j = 0; j < 8; j++) o[j] = f2b(acc[i][j]);
      *(u16x8*)&out[(size_t)n * 128 + tx8] = o;
    }
  }
}

// ---------------------------------------------------------------- pool + head
__global__ void find_starts(const int* __restrict__ batch, int* __restrict__ starts,
                            int N, int G) {
  int g = threadIdx.x;
  if (g > G) return;
  int lo = 0, hi = N;
  while (lo < hi) {
    int m = (lo + hi) >> 1;
    if (batch[m] < g) lo = m + 1; else hi = m;
  }
  starts[g] = lo;
}

__global__ void pool2(const unsigned short* __restrict__ h, const int* __restrict__ starts,
                      float* __restrict__ g, int G) {
  int gr = blockIdx.x / POOL_CHUNKS;
  int ck = blockIdx.x % POOL_CHUNKS;
  int c = threadIdx.x;
  int s = starts[gr], e = starts[gr + 1];
  int len = e - s;
  int a = s + (int)(((long long)len * ck) / POOL_CHUNKS);
  int b = s + (int)(((long long)len * (ck + 1)) / POOL_CHUNKS);
  float sum = 0.f;
  for (int n = a; n < b; n++) sum += b2f(h[(size_t)n * 128 + c]);
  if (b > a) atomicAdd(&g[gr * 128 + c], sum);
}

__global__ void head_kernel(const float* __restrict__ g, const float* __restrict__ W1,
                            const float* __restrict__ b1, const float* __restrict__ W2,
                            const float* __restrict__ b2, float* __restrict__ out) {
  int bg = blockIdx.x;
  int o = threadIdx.x;
  __shared__ float gs[128];
  __shared__ float red[128];
  gs[o] = g[bg * 128 + o];
  __syncthreads();
  float acc = b1[o];
  for (int k = 0; k < 128; k++) acc += gs[k] * W1[k * 128 + o];
  acc = fmaxf(acc, 0.f);
  red[o] = acc * W2[o];
  __syncthreads();
  for (int s = 64; s > 0; s >>= 1) {
    if (o < s) red[o] += red[o + s];
    __syncthreads();
  }
  if (o == 0) out[bg] = red[0] + b2[0];
}

// ---------------------------------------------------------------- launch
extern "C" void kernel_launch(void* const* d_in, const int* in_sizes, int n_in,
                              void* d_out, int out_size, void* d_ws, size_t ws_size,
                              hipStream_t stream) {
  const float* x = (const float*)d_in[0];
  const int* ei = (const int*)d_in[1];
  const int* ea = (const int*)d_in[2];
  const int* batch = (const int*)d_in[3];
  const float* embW = (const float*)d_in[4];
  const float* embB = (const float*)d_in[5];
  const float* Wrel = (const float*)d_in[6];
  const float* Wroot = (const float*)d_in[7];
  const float* rb = (const float*)d_in[8];
  const float* Wl = (const float*)d_in[9];
  const float* bl = (const float*)d_in[10];
  const float* Wr = (const float*)d_in[11];
  const float* l1W = (const float*)d_in[12];
  const float* l1b = (const float*)d_in[13];
  const float* l2W = (const float*)d_in[14];
  const float* l2b = (const float*)d_in[15];
  float* out = (float*)d_out;

  int N = in_sizes[0] / 32;
  int E = in_sizes[2];
  int G = out_size;
  int NSEG = N * 4;

  char* p = (char*)d_ws;
  auto alloc = [&](size_t bytes) {
    char* r = p;
    p += (bytes + 255) & ~(size_t)255;
    return r;
  };
  unsigned short* h_bf = (unsigned short*)alloc((size_t)N * 128 * 2);
  unsigned short* h2_bf = (unsigned short*)alloc((size_t)N * 128 * 2);
  unsigned short* ahat = (unsigned short*)alloc((size_t)N * 640 * 2);
  unsigned short* amf = (unsigned short*)alloc((size_t)N * 256 * 2);
  unsigned short* Btr = (unsigned short*)alloc((size_t)2 * 128 * 640 * 2);
  unsigned short* Btm = (unsigned short*)alloc((size_t)2 * 11 * 128 * 256 * 2);
  float* inv = (float*)alloc((size_t)NSEG * 4);
  int* cnt = (int*)alloc((size_t)NSEG * 4);
  int* seg_start = (int*)alloc((size_t)NSEG * 4);
  int* seg_cur = (int*)alloc((size_t)NSEG * 4);
  int* csr = (int*)alloc((size_t)E * 4);
  int* bucket = (int*)alloc((size_t)N * 4);
  int permCap = ((N + 63) / 64 + NBUCK) * 64;
  int* perm = (int*)alloc((size_t)permCap * 4);
  int* hist = (int*)alloc(64);
  int* off = (int*)alloc(64);
  int* fill = (int*)alloc(64);
  int* cursor = (int*)alloc(64);
  int* starts = (int*)alloc((size_t)(G + 1) * 4);
  float* g = (float*)alloc((size_t)G * 128 * 4);

  hipMemsetAsync(cnt, 0, (size_t)NSEG * 4, stream);
  hipMemsetAsync(hist, 0, 64, stream);
  hipMemsetAsync(cursor, 0, 64, stream);
  hipMemsetAsync(g, 0, (size_t)G * 128 * 4, stream);
  hipMemsetAsync(perm, 0xFF, (size_t)permCap * 4, stream);

  const int* src = ei;
  const int* dst = ei + E;

  count_edges<<<(E + 255) / 256, 256, 0, stream>>>(dst, ea, cnt, E);
  prep_nodes<<<(N + 255) / 256, 256, 0, stream>>>(cnt, inv, bucket, hist, N);
  calc_offsets<<<1, 64, 0, stream>>>(hist, off, fill);
  build_perm<<<(N + 255) / 256, 256, 0, stream>>>(bucket, fill, perm, N);
  assign_segments<<<(NSEG + 255) / 256, 256, 0, stream>>>(cnt, seg_start, seg_cur, cursor, NSEG);
  place_edges<<<(E + 255) / 256, 256, 0, stream>>>(src, dst, ea, seg_cur, csr, E);
  find_starts<<<1, 128, 0, stream>>>(batch, starts, N, G);
  conv_rgcn_w<<<(2 * 128 * 640 + 255) / 256, 256, 0, stream>>>(Wrel, Wroot, Btr);
  conv_mf_w<<<(2 * 11 * 128 * 256 + 255) / 256, 256, 0, stream>>>(Wl, Wr, Btm);

  int nb = (N + 63) / 64;
  embed_gemm<<<nb, 256, 0, stream>>>(x, embW, embB, h_bf, N);

  int mfblocks = permCap / 64;
  for (int blk = 0; blk < 2; blk++) {
    rgcn_gather<<<(N + 3) / 4, 256, 0, stream>>>(h_bf, csr, seg_start, cnt, inv, ahat, N);
    rgcn_mfma<<<nb, 256, 0, stream>>>(ahat, Btr + (size_t)blk * 81920, rb + blk * 128, h2_bf, N);
    mf_gather<<<(N + 3) / 4, 256, 0, stream>>>(h2_bf, csr, seg_start, cnt, amf, N);
    mf_mfma<<<mfblocks, 256, 0, stream>>>(amf, Btm + (size_t)blk * 11 * 128 * 256,
                                          bl + (size_t)blk * 11 * 128, perm, off, h_bf,
                                          (blk == 0) ? 1 : 0);
  }
  pool2<<<G * POOL_CHUNKS, 128, 0, stream>>>(h_bf, starts, g, G);
  head_kernel<<<G, 128, 0, stream>>>(g, l1W, l1b, l2W, l2b, out);
}

// Round 4
// 642.745 us; speedup vs baseline: 3.5896x; 1.2659x over previous
//
#include <hip/hip_runtime.h>
#include <hip/hip_bf16.h>

#define NRELS 4
#define MAXDEG 10
#define NBUCK 11
#define POOL_CHUNKS 8

typedef __attribute__((ext_vector_type(8))) short s16x8;
typedef __attribute__((ext_vector_type(4))) float f32x4;
typedef __attribute__((ext_vector_type(8))) unsigned short u16x8;

__device__ inline unsigned short f2b(float f) {
  __hip_bfloat16 h = __float2bfloat16(f);
  return *reinterpret_cast<unsigned short*>(&h);
}
__device__ inline float b2f(unsigned short u) {
  union { unsigned int i; float f; } v;
  v.i = ((unsigned int)u) << 16;
  return v.f;
}

typedef __attribute__((address_space(3))) unsigned int lds_uint;
typedef __attribute__((address_space(1))) const unsigned int glob_uint;
__device__ __forceinline__ void gld_lds16(const void* g, void* l) {
  // async global->LDS, 16 B/lane; LDS dest = wave-uniform base + lane*16
  __builtin_amdgcn_global_load_lds((glob_uint*)g, (lds_uint*)l, 16, 0, 0);
}

// ---------------------------------------------------------------- precompute
__global__ void count_edges(const int* __restrict__ dst, const int* __restrict__ rel,
                            int* __restrict__ cnt, int E) {
  int e = blockIdx.x * 256 + threadIdx.x;
  if (e < E) atomicAdd(&cnt[dst[e] * 4 + rel[e]], 1);
}

__global__ void prep_nodes(const int* __restrict__ cnt, float* __restrict__ inv,
                           int* __restrict__ bucket, int* __restrict__ hist, int N) {
  int n = blockIdx.x * 256 + threadIdx.x;
  int b = -1;
  if (n < N) {
    int d = 0;
    for (int r = 0; r < 4; r++) {
      int c = cnt[n * 4 + r];
      d += c;
      inv[n * 4 + r] = 1.0f / (float)(c > 1 ? c : 1);
    }
    b = d < MAXDEG ? d : MAXDEG;
    bucket[n] = b;
  }
  int lane = threadIdx.x & 63;
  for (int bb = 0; bb < NBUCK; bb++) {
    unsigned long long m = __ballot(b == bb);
    if (m == 0ULL) continue;
    int leader = __ffsll(m) - 1;
    if (lane == leader) atomicAdd(&hist[bb], __popcll(m));
  }
}

__global__ void calc_offsets(const int* __restrict__ hist, int* __restrict__ off,
                             int* __restrict__ fill) {
  if (threadIdx.x == 0) {
    int acc = 0;
    for (int b = 0; b < NBUCK; b++) {
      off[b] = acc;
      fill[b] = acc;
      acc += ((hist[b] + 63) >> 6) << 6;  // 64-aligned buckets; GEMM tiles are 64 rows
    }
    off[NBUCK] = acc;
  }
}

__global__ void build_perm(const int* __restrict__ bucket, int* __restrict__ fill,
                           int* __restrict__ perm, int N) {
  int n = blockIdx.x * 256 + threadIdx.x;
  int b = (n < N) ? bucket[n] : -1;
  int lane = threadIdx.x & 63;
  for (int bb = 0; bb < NBUCK; bb++) {
    unsigned long long m = __ballot(b == bb);
    if (m == 0ULL) continue;
    int leader = __ffsll(m) - 1;
    int base = 0;
    if (lane == leader) base = atomicAdd(&fill[bb], __popcll(m));
    base = __shfl(base, leader);
    if (b == bb) {
      int idx = __popcll(m & ((1ULL << lane) - 1ULL));
      perm[base + idx] = n;
    }
  }
}

__global__ void assign_segments(const int* __restrict__ cnt, int* __restrict__ seg_start,
                                int* __restrict__ seg_cur, int* __restrict__ cursor, int NSEG) {
  __shared__ int sd[256];
  __shared__ int sbase;
  int t = threadIdx.x;
  int s = blockIdx.x * 256 + t;
  int v = (s < NSEG) ? cnt[s] : 0;
  sd[t] = v;
  __syncthreads();
  for (int o = 1; o < 256; o <<= 1) {
    int x = (t >= o) ? sd[t - o] : 0;
    __syncthreads();
    sd[t] += x;
    __syncthreads();
  }
  if (t == 255) sbase = atomicAdd(cursor, sd[255]);
  __syncthreads();
  if (s < NSEG) {
    int st = sbase + sd[t] - v;
    seg_start[s] = st;
    seg_cur[s] = st;
  }
}

__global__ void place_edges(const int* __restrict__ src, const int* __restrict__ dst,
                            const int* __restrict__ rel, int* __restrict__ seg_cur,
                            int* __restrict__ csr, int E) {
  int e = blockIdx.x * 256 + threadIdx.x;
  if (e >= E) return;
  int seg = dst[e] * 4 + rel[e];
  int pos = atomicAdd(&seg_cur[seg], 1);
  csr[pos] = src[e];
}

// ---------------------------------------------------------------- weight conversion
__global__ void conv_rgcn_w(const float* __restrict__ Wrel, const float* __restrict__ Wroot,
                            unsigned short* __restrict__ Bt) {
  int t = blockIdx.x * 256 + threadIdx.x;
  if (t >= 2 * 128 * 640) return;
  int blk = t / 81920;
  int rem = t % 81920;
  int n = rem / 640;
  int k = rem % 640;
  float v;
  if (k < 512)
    v = Wrel[(size_t)blk * 65536 + (size_t)k * 128 + n];
  else
    v = Wroot[(size_t)blk * 16384 + (size_t)(k - 512) * 128 + n];
  Bt[t] = f2b(v);
}

__global__ void conv_mf_w(const float* __restrict__ Wl, const float* __restrict__ Wr,
                          unsigned short* __restrict__ Btm) {
  int t = blockIdx.x * 256 + threadIdx.x;
  if (t >= 2 * 11 * 128 * 256) return;
  int k = t & 255;
  int n = (t >> 8) & 127;
  int bb = (t >> 15) % 11;
  int blk = t / (11 * 128 * 256);
  float v;
  if (k < 128)
    v = Wl[(((size_t)blk * 11 + bb) * 128 + k) * 128 + n];
  else
    v = Wr[(((size_t)blk * 11 + bb) * 128 + (k - 128)) * 128 + n];
  Btm[t] = f2b(v);
}

// ---------------------------------------------------------------- gathers (bf16)
__global__ void rgcn_gather(const unsigned short* __restrict__ hb, const int* __restrict__ csr,
                            const int* __restrict__ seg_start, const int* __restrict__ cnt,
                            const float* __restrict__ inv, unsigned short* __restrict__ ahat,
                            int N) {
  int n = blockIdx.x * 4 + (threadIdx.x >> 6);
  if (n >= N) return;
  int c2 = (threadIdx.x & 63) * 2;
#pragma unroll
  for (int r = 0; r < 4; r++) {
    int seg = n * 4 + r;
    int st = seg_start[seg], cn = cnt[seg];
    float s0 = 0.f, s1 = 0.f;
    int i = 0;
    for (; i + 2 <= cn; i += 2) {
      int p0 = csr[st + i], p1 = csr[st + i + 1];
      unsigned int v0 = *(const unsigned int*)(hb + (size_t)p0 * 128 + c2);
      unsigned int v1 = *(const unsigned int*)(hb + (size_t)p1 * 128 + c2);
      s0 += b2f(v0 & 0xffff) + b2f(v1 & 0xffff);
      s1 += b2f(v0 >> 16) + b2f(v1 >> 16);
    }
    if (i < cn) {
      unsigned int v0 = *(const unsigned int*)(hb + (size_t)csr[st + i] * 128 + c2);
      s0 += b2f(v0 & 0xffff);
      s1 += b2f(v0 >> 16);
    }
    float w = inv[seg];
    unsigned int o = (unsigned int)f2b(s0 * w) | ((unsigned int)f2b(s1 * w) << 16);
    *(unsigned int*)(ahat + (size_t)n * 640 + r * 128 + c2) = o;
  }
  *(unsigned int*)(ahat + (size_t)n * 640 + 512 + c2) =
      *(const unsigned int*)(hb + (size_t)n * 128 + c2);
}

// writes A pre-permuted: amf[i] = gather(perm[i]) so the GEMM A-side is contiguous
__global__ void mf_gather(const unsigned short* __restrict__ hb, const int* __restrict__ csr,
                          const int* __restrict__ seg_start, const int* __restrict__ cnt,
                          const int* __restrict__ perm, unsigned short* __restrict__ amf,
                          int total) {
  int i = blockIdx.x * 4 + (threadIdx.x >> 6);
  if (i >= total) return;
  int c2 = (threadIdx.x & 63) * 2;
  int n = perm[i];
  if (n < 0) {
    *(unsigned int*)(amf + (size_t)i * 256 + c2) = 0u;
    *(unsigned int*)(amf + (size_t)i * 256 + 128 + c2) = 0u;
    return;
  }
  float s0 = 0.f, s1 = 0.f;
#pragma unroll
  for (int r = 0; r < 4; r++) {
    int seg = n * 4 + r;
    int st = seg_start[seg], cn = cnt[seg];
    int i2 = 0;
    for (; i2 + 2 <= cn; i2 += 2) {
      int p0 = csr[st + i2], p1 = csr[st + i2 + 1];
      unsigned int v0 = *(const unsigned int*)(hb + (size_t)p0 * 128 + c2);
      unsigned int v1 = *(const unsigned int*)(hb + (size_t)p1 * 128 + c2);
      s0 += b2f(v0 & 0xffff) + b2f(v1 & 0xffff);
      s1 += b2f(v0 >> 16) + b2f(v1 >> 16);
    }
    if (i2 < cn) {
      unsigned int v0 = *(const unsigned int*)(hb + (size_t)csr[st + i2] * 128 + c2);
      s0 += b2f(v0 & 0xffff);
      s1 += b2f(v0 >> 16);
    }
  }
  unsigned int o = (unsigned int)f2b(s0) | ((unsigned int)f2b(s1) << 16);
  *(unsigned int*)(amf + (size_t)i * 256 + c2) = o;
  *(unsigned int*)(amf + (size_t)i * 256 + 128 + c2) =
      *(const unsigned int*)(hb + (size_t)n * 128 + c2);
}

// ---------------------------------------------------------------- tiled MFMA GEMMs
// Block: 64 rows x 128 cols, BK=64, 256 threads (4 waves), wave = 64x32.
// LDS: As[64][64] 8KB, Bs[128][64] 16KB, 16B-chunk XOR swizzle (chunk c stored at c^(row&7)).
__global__ __launch_bounds__(256) void rgcn_mfma(const unsigned short* __restrict__ A,
                                                 const unsigned short* __restrict__ Bt,
                                                 const float* __restrict__ bias,
                                                 unsigned short* __restrict__ out, int N) {
  __shared__ unsigned char As[8192];
  __shared__ unsigned char Bs[16384];
  int t = threadIdx.x;
  int lane = t & 63, wave = t >> 6;
  int row = lane & 15, quad = lane >> 4;
  int m0 = blockIdx.x * 64;
  int nh = wave * 32;
  f32x4 acc[2][4];
#pragma unroll
  for (int i = 0; i < 2; i++)
#pragma unroll
    for (int j = 0; j < 4; j++) acc[i][j] = (f32x4){0.f, 0.f, 0.f, 0.f};

  for (int kt = 0; kt < 10; kt++) {
    int kb2 = kt * 128;  // byte offset of k-chunk in a row (64 elem * 2B)
#pragma unroll
    for (int s = 0; s < 2; s++) {  // A: 8KB
      int o = s * 4096 + t * 16;
      int r = o >> 7, c = ((o >> 4) & 7) ^ (r & 7);
      int gr = m0 + r;
      if (gr >= N) gr = N - 1;
      gld_lds16((const char*)A + (size_t)gr * 1280 + kb2 + c * 16, As + o);
    }
#pragma unroll
    for (int s = 0; s < 4; s++) {  // B: 16KB
      int o = s * 4096 + t * 16;
      int r = o >> 7, c = ((o >> 4) & 7) ^ (r & 7);
      gld_lds16((const char*)Bt + (size_t)r * 1280 + kb2 + c * 16, Bs + o);
    }
    __syncthreads();
#pragma unroll
    for (int ks = 0; ks < 2; ks++) {
      int cch = ks * 4 + quad;
      s16x8 af[4], bf[2];
#pragma unroll
      for (int mt = 0; mt < 4; mt++) {
        int R = mt * 16 + row;
        af[mt] = *(const s16x8*)(As + R * 128 + ((cch ^ (R & 7)) << 4));
      }
#pragma unroll
      for (int nt = 0; nt < 2; nt++) {
        int R = nh + nt * 16 + row;
        bf[nt] = *(const s16x8*)(Bs + R * 128 + ((cch ^ (R & 7)) << 4));
      }
#pragma unroll
      for (int nt = 0; nt < 2; nt++)
#pragma unroll
        for (int mt = 0; mt < 4; mt++)
          acc[nt][mt] = __builtin_amdgcn_mfma_f32_16x16x32_bf16(af[mt], bf[nt], acc[nt][mt], 0, 0, 0);
    }
    __syncthreads();
  }
#pragma unroll
  for (int nt = 0; nt < 2; nt++) {
    int n = nh + nt * 16 + row;
    float bv = bias[n];
#pragma unroll
    for (int mt = 0; mt < 4; mt++) {
#pragma unroll
      for (int r4 = 0; r4 < 4; r4++) {
        int m = m0 + mt * 16 + quad * 4 + r4;
        if (m < N) out[(size_t)m * 128 + n] = f2b(fmaxf(acc[nt][mt][r4] + bv, 0.f));
      }
    }
  }
}

__global__ __launch_bounds__(256) void mf_mfma(const unsigned short* __restrict__ A,
                                               const unsigned short* __restrict__ Bt,
                                               const float* __restrict__ bl,
                                               const int* __restrict__ perm,
                                               const int* __restrict__ off,
                                               unsigned short* __restrict__ out, int relu_out) {
  __shared__ unsigned char As[8192];
  __shared__ unsigned char Bs[16384];
  __shared__ int soff[12];
  __shared__ int nodes[64];
  int t = threadIdx.x;
  int m0 = blockIdx.x * 64;
  if (t < 12) soff[t] = off[t];
  if (t >= 64 && t < 128) nodes[t - 64] = perm[m0 + t - 64];
  __syncthreads();
  if (m0 >= soff[11]) return;
  int b = 0;
  while (b < 10 && m0 >= soff[b + 1]) b++;
  const unsigned short* Bb = Bt + (size_t)b * 128 * 256;
  const float* bb = bl + b * 128;
  int lane = t & 63, wave = t >> 6;
  int row = lane & 15, quad = lane >> 4;
  int nh = wave * 32;
  f32x4 acc[2][4];
#pragma unroll
  for (int i = 0; i < 2; i++)
#pragma unroll
    for (int j = 0; j < 4; j++) acc[i][j] = (f32x4){0.f, 0.f, 0.f, 0.f};

  for (int kt = 0; kt < 4; kt++) {
    int kb2 = kt * 128;
#pragma unroll
    for (int s = 0; s < 2; s++) {
      int o = s * 4096 + t * 16;
      int r = o >> 7, c = ((o >> 4) & 7) ^ (r & 7);
      gld_lds16((const char*)A + (size_t)(m0 + r) * 512 + kb2 + c * 16, As + o);
    }
#pragma unroll
    for (int s = 0; s < 4; s++) {
      int o = s * 4096 + t * 16;
      int r = o >> 7, c = ((o >> 4) & 7) ^ (r & 7);
      gld_lds16((const char*)Bb + (size_t)r * 512 + kb2 + c * 16, Bs + o);
    }
    __syncthreads();
#pragma unroll
    for (int ks = 0; ks < 2; ks++) {
      int cch = ks * 4 + quad;
      s16x8 af[4], bf[2];
#pragma unroll
      for (int mt = 0; mt < 4; mt++) {
        int R = mt * 16 + row;
        af[mt] = *(const s16x8*)(As + R * 128 + ((cch ^ (R & 7)) << 4));
      }
#pragma unroll
      for (int nt = 0; nt < 2; nt++) {
        int R = nh + nt * 16 + row;
        bf[nt] = *(const s16x8*)(Bs + R * 128 + ((cch ^ (R & 7)) << 4));
      }
#pragma unroll
      for (int nt = 0; nt < 2; nt++)
#pragma unroll
        for (int mt = 0; mt < 4; mt++)
          acc[nt][mt] = __builtin_amdgcn_mfma_f32_16x16x32_bf16(af[mt], bf[nt], acc[nt][mt], 0, 0, 0);
    }
    __syncthreads();
  }
#pragma unroll
  for (int nt = 0; nt < 2; nt++) {
    int n = nh + nt * 16 + row;
    float bv = bb[n];
#pragma unroll
    for (int mt = 0; mt < 4; mt++) {
#pragma unroll
      for (int r4 = 0; r4 < 4; r4++) {
        int nd = nodes[mt * 16 + quad * 4 + r4];
        if (nd >= 0) {
          float v = acc[nt][mt][r4] + bv;
          if (relu_out) v = fmaxf(v, 0.f);
          out[(size_t)nd * 128 + n] = f2b(v);
        }
      }
    }
  }
}

// ---------------------------------------------------------------- embed (fp32 compute, bf16 out)
__global__ __launch_bounds__(256) void embed_gemm(const float* __restrict__ x,
                                                  const float* __restrict__ W,
                                                  const float* __restrict__ bias,
                                                  unsigned short* __restrict__ out, int N) {
  __shared__ float As[64][33];
  __shared__ float Ws[32][128];
  int tid = threadIdx.x;
  int row0 = blockIdx.x * 64;
  int tx = tid & 15, ty = tid >> 4;
  int tx8 = tx * 8, ty4 = ty * 4;
  float acc[4][8];
#pragma unroll
  for (int j = 0; j < 8; j++) {
    float bv = bias[tx8 + j];
#pragma unroll
    for (int i = 0; i < 4; i++) acc[i][j] = bv;
  }
#pragma unroll
  for (int l = 0; l < 8; l++) {
    int lin = tid + l * 256;
    int r = lin >> 5, kk = lin & 31;
    int n = row0 + r;
    As[r][kk] = (n < N) ? x[(size_t)n * 32 + kk] : 0.f;
  }
#pragma unroll
  for (int l = 0; l < 16; l++) {
    int lin = tid + l * 256;
    Ws[lin >> 7][lin & 127] = W[lin];
  }
  __syncthreads();
#pragma unroll
  for (int kk = 0; kk < 32; kk++) {
    float a[4];
#pragma unroll
    for (int i = 0; i < 4; i++) a[i] = As[ty4 + i][kk];
    float4 w0 = *(const float4*)&Ws[kk][tx8];
    float4 w1 = *(const float4*)&Ws[kk][tx8 + 4];
    float w[8] = {w0.x, w0.y, w0.z, w0.w, w1.x, w1.y, w1.z, w1.w};
#pragma unroll
    for (int i = 0; i < 4; i++)
#pragma unroll
      for (int j = 0; j < 8; j++) acc[i][j] += a[i] * w[j];
  }
#pragma unroll
  for (int i = 0; i < 4; i++) {
    int n = row0 + ty4 + i;
    if (n < N) {
      u16x8 o;
#pragma unroll
      for (int j = 0; j < 8; j++) o[j] = f2b(acc[i][j]);
      *(u16x8*)&out[(size_t)n * 128 + tx8] = o;
    }
  }
}

// ---------------------------------------------------------------- pool + head
__global__ void find_starts(const int* __restrict__ batch, int* __restrict__ starts,
                            int N, int G) {
  int g = threadIdx.x;
  if (g > G) return;
  int lo = 0, hi = N;
  while (lo < hi) {
    int m = (lo + hi) >> 1;
    if (batch[m] < g) lo = m + 1; else hi = m;
  }
  starts[g] = lo;
}

__global__ void pool2(const unsigned short* __restrict__ h, const int* __restrict__ starts,
                      float* __restrict__ g, int G) {
  int gr = blockIdx.x / POOL_CHUNKS;
  int ck = blockIdx.x % POOL_CHUNKS;
  int c = threadIdx.x;
  int s = starts[gr], e = starts[gr + 1];
  int len = e - s;
  int a = s + (int)(((long long)len * ck) / POOL_CHUNKS);
  int b = s + (int)(((long long)len * (ck + 1)) / POOL_CHUNKS);
  float sum = 0.f;
  for (int n = a; n < b; n++) sum += b2f(h[(size_t)n * 128 + c]);
  if (b > a) atomicAdd(&g[gr * 128 + c], sum);
}

__global__ void head_kernel(const float* __restrict__ g, const float* __restrict__ W1,
                            const float* __restrict__ b1, const float* __restrict__ W2,
                            const float* __restrict__ b2, float* __restrict__ out) {
  int bg = blockIdx.x;
  int o = threadIdx.x;
  __shared__ float gs[128];
  __shared__ float red[128];
  gs[o] = g[bg * 128 + o];
  __syncthreads();
  float acc = b1[o];
  for (int k = 0; k < 128; k++) acc += gs[k] * W1[k * 128 + o];
  acc = fmaxf(acc, 0.f);
  red[o] = acc * W2[o];
  __syncthreads();
  for (int s = 64; s > 0; s >>= 1) {
    if (o < s) red[o] += red[o + s];
    __syncthreads();
  }
  if (o == 0) out[bg] = red[0] + b2[0];
}

// ---------------------------------------------------------------- launch
extern "C" void kernel_launch(void* const* d_in, const int* in_sizes, int n_in,
                              void* d_out, int out_size, void* d_ws, size_t ws_size,
                              hipStream_t stream) {
  const float* x = (const float*)d_in[0];
  const int* ei = (const int*)d_in[1];
  const int* ea = (const int*)d_in[2];
  const int* batch = (const int*)d_in[3];
  const float* embW = (const float*)d_in[4];
  const float* embB = (const float*)d_in[5];
  const float* Wrel = (const float*)d_in[6];
  const float* Wroot = (const float*)d_in[7];
  const float* rb = (const float*)d_in[8];
  const float* Wl = (const float*)d_in[9];
  const float* bl = (const float*)d_in[10];
  const float* Wr = (const float*)d_in[11];
  const float* l1W = (const float*)d_in[12];
  const float* l1b = (const float*)d_in[13];
  const float* l2W = (const float*)d_in[14];
  const float* l2b = (const float*)d_in[15];
  float* out = (float*)d_out;

  int N = in_sizes[0] / 32;
  int E = in_sizes[2];
  int G = out_size;
  int NSEG = N * 4;

  char* p = (char*)d_ws;
  auto alloc = [&](size_t bytes) {
    char* r = p;
    p += (bytes + 255) & ~(size_t)255;
    return r;
  };
  int permCap = ((N + 63) / 64 + NBUCK) * 64;
  unsigned short* h_bf = (unsigned short*)alloc((size_t)N * 128 * 2);
  unsigned short* h2_bf = (unsigned short*)alloc((size_t)N * 128 * 2);
  unsigned short* ahat = (unsigned short*)alloc((size_t)N * 640 * 2);
  unsigned short* amf = (unsigned short*)alloc((size_t)permCap * 256 * 2);
  unsigned short* Btr = (unsigned short*)alloc((size_t)2 * 128 * 640 * 2);
  unsigned short* Btm = (unsigned short*)alloc((size_t)2 * 11 * 128 * 256 * 2);
  float* inv = (float*)alloc((size_t)NSEG * 4);
  int* cnt = (int*)alloc((size_t)NSEG * 4);
  int* seg_start = (int*)alloc((size_t)NSEG * 4);
  int* seg_cur = (int*)alloc((size_t)NSEG * 4);
  int* csr = (int*)alloc((size_t)E * 4);
  int* bucket = (int*)alloc((size_t)N * 4);
  int* perm = (int*)alloc((size_t)permCap * 4);
  int* hist = (int*)alloc(64);
  int* off = (int*)alloc(64);
  int* fill = (int*)alloc(64);
  int* cursor = (int*)alloc(64);
  int* starts = (int*)alloc((size_t)(G + 1) * 4);
  float* g = (float*)alloc((size_t)G * 128 * 4);

  hipMemsetAsync(cnt, 0, (size_t)NSEG * 4, stream);
  hipMemsetAsync(hist, 0, 64, stream);
  hipMemsetAsync(cursor, 0, 64, stream);
  hipMemsetAsync(g, 0, (size_t)G * 128 * 4, stream);
  hipMemsetAsync(perm, 0xFF, (size_t)permCap * 4, stream);

  const int* src = ei;
  const int* dst = ei + E;

  count_edges<<<(E + 255) / 256, 256, 0, stream>>>(dst, ea, cnt, E);
  prep_nodes<<<(N + 255) / 256, 256, 0, stream>>>(cnt, inv, bucket, hist, N);
  calc_offsets<<<1, 64, 0, stream>>>(hist, off, fill);
  build_perm<<<(N + 255) / 256, 256, 0, stream>>>(bucket, fill, perm, N);
  assign_segments<<<(NSEG + 255) / 256, 256, 0, stream>>>(cnt, seg_start, seg_cur, cursor, NSEG);
  place_edges<<<(E + 255) / 256, 256, 0, stream>>>(src, dst, ea, seg_cur, csr, E);
  find_starts<<<1, 128, 0, stream>>>(batch, starts, N, G);
  conv_rgcn_w<<<(2 * 128 * 640 + 255) / 256, 256, 0, stream>>>(Wrel, Wroot, Btr);
  conv_mf_w<<<(2 * 11 * 128 * 256 + 255) / 256, 256, 0, stream>>>(Wl, Wr, Btm);

  int nb = (N + 63) / 64;
  embed_gemm<<<nb, 256, 0, stream>>>(x, embW, embB, h_bf, N);

  int mfblocks = permCap / 64;
  for (int blk = 0; blk < 2; blk++) {
    rgcn_gather<<<(N + 3) / 4, 256, 0, stream>>>(h_bf, csr, seg_start, cnt, inv, ahat, N);
    rgcn_mfma<<<nb, 256, 0, stream>>>(ahat, Btr + (size_t)blk * 81920, rb + blk * 128, h2_bf, N);
    mf_gather<<<(permCap + 3) / 4, 256, 0, stream>>>(h2_bf, csr, seg_start, cnt, perm, amf,
                                                     permCap);
    mf_mfma<<<mfblocks, 256, 0, stream>>>(amf, Btm + (size_t)blk * 11 * 128 * 256,
                                          bl + (size_t)blk * 11 * 128, perm, off, h_bf,
                                          (blk == 0) ? 1 : 0);
  }
  pool2<<<G * POOL_CHUNKS, 128, 0, stream>>>(h_bf, starts, g, G);
  head_kernel<<<G, 128, 0, stream>>>(g, l1W, l1b, l2W, l2b, out);
}